// Round 5
// baseline (351.874 us; speedup 1.0000x reference)
//
#include <hip/hip_runtime.h>

#define T_TOK 4096
#define H_DIM 512
#define I_DIM 1024
#define E_NUM 32
#define KTOP  2
#define CAP   512
#define NROWS (E_NUM * CAP)    // 16384
#define NPAIR (T_TOK * KTOP)   // 8192

typedef __attribute__((ext_vector_type(8))) short short8;    // 8 bf16 = 4 VGPRs
typedef __attribute__((ext_vector_type(4))) float float4v;
typedef __attribute__((ext_vector_type(4))) unsigned int uint4v;

__device__ __forceinline__ unsigned short f2bf_rne(float f) {
  unsigned int u = __float_as_uint(f);
  u += 0x7FFFu + ((u >> 16) & 1u);
  return (unsigned short)(u >> 16);
}
__device__ __forceinline__ unsigned int pack_bf2(float a, float b) {
  return (unsigned int)f2bf_rne(a) | ((unsigned int)f2bf_rne(b) << 16);
}
__device__ __forceinline__ float bf2f(unsigned short s) {
  return __uint_as_float(((unsigned int)s) << 16);
}

#define GLOAD_LDS16(gptr, lptr)                                                         \
  __builtin_amdgcn_global_load_lds((const __attribute__((address_space(1))) unsigned int*)(gptr), \
                                   (__attribute__((address_space(3))) unsigned int*)(lptr), 16, 0, 0)

// ---------------- routing ----------------
__global__ void k_route(const int* __restrict__ idx, int* __restrict__ counts,
                        int* __restrict__ slot_token, int* __restrict__ inv) {
  int i = blockIdx.x * 256 + threadIdx.x;
  if (i >= NPAIR) return;
  int e = idx[i];
  int p = atomicAdd(counts + e, 1);
  if (p < CAP) {
    slot_token[e * CAP + p] = i >> 1;  // KTOP == 2
    inv[i] = e * CAP + p;
  } else {
    inv[i] = -1;
  }
}

// ---------------- gather tokens -> bf16 dispatch buffer (early-exit padded rows) ----
__global__ void k_gather(const float* __restrict__ hs, const int* __restrict__ counts,
                         const int* __restrict__ slot_token, unsigned short* __restrict__ xd) {
  const int r = blockIdx.x * 4 + (threadIdx.x >> 6);  // one wave per row
  const int lane = threadIdx.x & 63;
  const int e = r >> 9;
  const int p = r & (CAP - 1);
  const int cnt = min(counts[e], CAP);
  if (p >= ((cnt + 127) & ~127)) return;  // beyond last active tile: never read
  uint4v v = {0u, 0u, 0u, 0u};
  if (p < cnt) {
    const int t = slot_token[r];
    const float4v* src = (const float4v*)(hs + (size_t)t * H_DIM);
    float4v f0 = src[lane * 2];
    float4v f1 = src[lane * 2 + 1];
    v.x = pack_bf2(f0.x, f0.y);
    v.y = pack_bf2(f0.z, f0.w);
    v.z = pack_bf2(f1.x, f1.y);
    v.w = pack_bf2(f1.z, f1.w);
  }
  *(uint4v*)(xd + (size_t)r * H_DIM + lane * 8) = v;
}

// ---------------- GEMM1 (persistent-B): one block per (expert, 64-col tile).
// B panel (64 gate + 64 up cols x K=512) converted fp32->bf16 into LDS ONCE,
// then loop over the expert's active 128-row tiles streaming A via
// global_load_lds with the depth-2 counted-vmcnt pipeline.
// LDS: panel 128KB + 3 x 8KB A buffers = 152KB (1 block/CU).
__global__ __launch_bounds__(256, 1) void k_gemm1(const unsigned short* __restrict__ xd,
                                                  const float* __restrict__ gup,
                                                  const int* __restrict__ counts,
                                                  unsigned short* __restrict__ act) {
  __shared__ unsigned short lds[77824];  // 65536 panel + 3*4096 A = 152KB
  unsigned short* panel = lds;
  unsigned short* ab0 = lds + 65536;
  unsigned short* ab1 = lds + 69632;
  unsigned short* ab2 = lds + 73728;

  // XCD affinity: hw maps wg i -> XCD i%8. 64 blocks/XCD = 4 experts x 16 col tiles.
  const int bid = blockIdx.x;            // 512 blocks
  const int xcd = bid & 7, slot = bid >> 3;        // slot 0..63
  const int e = xcd + 8 * (slot >> 4);             // experts {xcd, xcd+8, xcd+16, xcd+24}
  const int c0 = (slot & 15) * 64;                 // 16 col tiles over I
  const int cnt = min(counts[e], CAP);
  const int nrt = (cnt + 127) >> 7;                // active 128-row tiles
  if (nrt == 0) return;

  const int tid = threadIdx.x;
  const int lane = tid & 63;
  const int wid = tid >> 6;
  const int wr = wid >> 1, wc = wid & 1;   // wave tile: 64 rows x 32 cols (of 64)
  const int ml = lane & 15, kg = lane >> 4;

  // ---- one-time panel fill: rows 0..63 = gate cols, 64..127 = up cols ----
  // LDS chunk layout (8 bf16 = 16B): chunk = kc*128 + n, kc in [0,64), n in [0,128)
  {
    const int r = tid >> 1;       // 0..127 panel row
    const int h = tid & 1;        // K half (256 fp32)
    const float* wrow = gup + (size_t)e * (2 * I_DIM * H_DIM) +
        ((r < 64) ? (size_t)(c0 + r) * H_DIM
                  : (size_t)(I_DIM + c0 + (r - 64)) * H_DIM) + h * 256;
#pragma unroll 4
    for (int j = 0; j < 32; ++j) {
      float4v f0 = *(const float4v*)(wrow + j * 8);
      float4v f1 = *(const float4v*)(wrow + j * 8 + 4);
      uint4v v;
      v.x = pack_bf2(f0.x, f0.y); v.y = pack_bf2(f0.z, f0.w);
      v.z = pack_bf2(f1.x, f1.y); v.w = pack_bf2(f1.z, f1.w);
      *(uint4v*)(panel + (size_t)((h * 32 + j) * 128 + r) * 8) = v;
    }
  }
  __syncthreads();

  // A staging geometry (per K-step of 32): 512 chunks; thread stages tid & 256+tid
  const int rowA = tid & 127, kcA = tid >> 7;
  const int dA0 = (wid * 64) * 8;          // wave-uniform LDS base; DMA adds lane*16B
  const int dA1 = (256 + wid * 64) * 8;

#pragma unroll 1
  for (int rt = 0; rt < nrt; ++rt) {
    const int r0 = e * CAP + rt * 128;
    const unsigned short* a_src = xd + (size_t)(r0 + rowA) * H_DIM + kcA * 8;

    float4v accg[4][2] = {};
    float4v accu[4][2] = {};

    auto STAGE = [&](unsigned short* lb, int t) {
      GLOAD_LDS16(a_src + t * 32, lb + dA0);
      GLOAD_LDS16(a_src + t * 32 + 16, lb + dA1);
    };
    auto COMPUTE = [&](const unsigned short* lb, int t) {
      short8 af[4], bg[2], bu[2];
#pragma unroll
      for (int mi = 0; mi < 4; ++mi)
        af[mi] = *(const short8*)(lb + (kg * 128 + wr * 64 + mi * 16 + ml) * 8);
#pragma unroll
      for (int ni = 0; ni < 2; ++ni) {
        const int n = wc * 32 + ni * 16 + ml;
        bg[ni] = *(const short8*)(panel + ((t * 4 + kg) * 128 + n) * 8);
        bu[ni] = *(const short8*)(panel + ((t * 4 + kg) * 128 + n + 64) * 8);
      }
#pragma unroll
      for (int mi = 0; mi < 4; ++mi)
#pragma unroll
        for (int ni = 0; ni < 2; ++ni) {
          accg[mi][ni] = __builtin_amdgcn_mfma_f32_16x16x32_bf16(af[mi], bg[ni], accg[mi][ni], 0, 0, 0);
          accu[mi][ni] = __builtin_amdgcn_mfma_f32_16x16x32_bf16(af[mi], bu[ni], accu[mi][ni], 0, 0, 0);
        }
    };

    __syncthreads();                       // all waves done with prev rt's buffers
    unsigned short *p0 = ab0, *p1 = ab1, *p2 = ab2;
    STAGE(p0, 0);
    STAGE(p1, 1);
#pragma unroll 1
    for (int t = 0; t < 14; ++t) {         // NT = H/32 = 16
      asm volatile("s_waitcnt vmcnt(2)" ::: "memory");  // own tile-t loads landed
      __builtin_amdgcn_s_barrier();                      // => ALL waves' tile-t landed
      __builtin_amdgcn_sched_barrier(0);
      STAGE(p2, t + 2);                    // overwrites buffer computed at t-1
      COMPUTE(p0, t);
      unsigned short* tmp = p0; p0 = p1; p1 = p2; p2 = tmp;
    }
    asm volatile("s_waitcnt vmcnt(2)" ::: "memory");    // t = 14
    __builtin_amdgcn_s_barrier();
    __builtin_amdgcn_sched_barrier(0);
    COMPUTE(p0, 14);
    asm volatile("s_waitcnt vmcnt(0)" ::: "memory");    // t = 15 (drain)
    __builtin_amdgcn_s_barrier();
    __builtin_amdgcn_sched_barrier(0);
    COMPUTE(p1, 15);

    // epilogue: act = silu(g)*u, bf16
#pragma unroll
    for (int mi = 0; mi < 4; ++mi) {
      const int row = r0 + wr * 64 + mi * 16 + kg * 4;
#pragma unroll
      for (int ni = 0; ni < 2; ++ni) {
        const int col = c0 + wc * 32 + ni * 16 + ml;
#pragma unroll
        for (int rj = 0; rj < 4; ++rj) {
          float g = accg[mi][ni][rj];
          float u = accu[mi][ni][rj];
          float a = (g / (1.0f + __expf(-g))) * u;
          act[(size_t)(row + rj) * I_DIM + col] = f2bf_rne(a);
        }
      }
    }
  }
}

// ---------------- GEMM2 (persistent-B): one block per (expert, 64-col tile of H).
// B panel 64 cols x K=1024 bf16 in LDS (128KB); loop row tiles streaming A.
__global__ __launch_bounds__(256, 1) void k_gemm2(const unsigned short* __restrict__ act,
                                                  const float* __restrict__ dwn,
                                                  const int* __restrict__ counts,
                                                  unsigned short* __restrict__ yd) {
  __shared__ unsigned short lds[77824];  // 65536 panel + 3*4096 A = 152KB
  unsigned short* panel = lds;
  unsigned short* ab0 = lds + 65536;
  unsigned short* ab1 = lds + 69632;
  unsigned short* ab2 = lds + 73728;

  const int bid = blockIdx.x;            // 256 blocks (1 per CU)
  const int xcd = bid & 7, slot = bid >> 3;        // slot 0..31
  const int e = xcd + 8 * (slot >> 3);             // 4 experts per XCD
  const int c0 = (slot & 7) * 64;                  // 8 col tiles over H
  const int cnt = min(counts[e], CAP);
  const int nrt = (cnt + 127) >> 7;
  if (nrt == 0) return;

  const int tid = threadIdx.x;
  const int lane = tid & 63;
  const int wid = tid >> 6;
  const int wr = wid >> 1, wc = wid & 1;
  const int ml = lane & 15, kg = lane >> 4;

  // ---- one-time panel fill: 64 rows x K=1024 ----
  // LDS chunk = kc*64 + n, kc in [0,128), n in [0,64)
  {
    const int r = tid >> 2;       // 0..63 panel row
    const int q = tid & 3;        // K quarter (256 fp32)
    const float* wrow = dwn + (size_t)e * (H_DIM * I_DIM) + (size_t)(c0 + r) * I_DIM + q * 256;
#pragma unroll 4
    for (int j = 0; j < 32; ++j) {
      float4v f0 = *(const float4v*)(wrow + j * 8);
      float4v f1 = *(const float4v*)(wrow + j * 8 + 4);
      uint4v v;
      v.x = pack_bf2(f0.x, f0.y); v.y = pack_bf2(f0.z, f0.w);
      v.z = pack_bf2(f1.x, f1.y); v.w = pack_bf2(f1.z, f1.w);
      *(uint4v*)(panel + (size_t)((q * 32 + j) * 64 + r) * 8) = v;
    }
  }
  __syncthreads();

  const int rowA = tid & 127, kcA = tid >> 7;
  const int dA0 = (wid * 64) * 8;
  const int dA1 = (256 + wid * 64) * 8;

#pragma unroll 1
  for (int rt = 0; rt < nrt; ++rt) {
    const int r0 = e * CAP + rt * 128;
    const unsigned short* a_src = act + (size_t)(r0 + rowA) * I_DIM + kcA * 8;

    float4v acc[4][2] = {};

    auto STAGE = [&](unsigned short* lb, int t) {
      GLOAD_LDS16(a_src + t * 32, lb + dA0);
      GLOAD_LDS16(a_src + t * 32 + 16, lb + dA1);
    };
    auto COMPUTE = [&](const unsigned short* lb, int t) {
      short8 af[4], bf[2];
#pragma unroll
      for (int mi = 0; mi < 4; ++mi)
        af[mi] = *(const short8*)(lb + (kg * 128 + wr * 64 + mi * 16 + ml) * 8);
#pragma unroll
      for (int ni = 0; ni < 2; ++ni)
        bf[ni] = *(const short8*)(panel + ((t * 4 + kg) * 64 + wc * 32 + ni * 16 + ml) * 8);
#pragma unroll
      for (int mi = 0; mi < 4; ++mi)
#pragma unroll
        for (int ni = 0; ni < 2; ++ni)
          acc[mi][ni] = __builtin_amdgcn_mfma_f32_16x16x32_bf16(af[mi], bf[ni], acc[mi][ni], 0, 0, 0);
    };

    __syncthreads();
    unsigned short *p0 = ab0, *p1 = ab1, *p2 = ab2;
    STAGE(p0, 0);
    STAGE(p1, 1);
#pragma unroll 1
    for (int t = 0; t < 30; ++t) {         // NT = I/32 = 32
      asm volatile("s_waitcnt vmcnt(2)" ::: "memory");
      __builtin_amdgcn_s_barrier();
      __builtin_amdgcn_sched_barrier(0);
      STAGE(p2, t + 2);
      COMPUTE(p0, t);
      unsigned short* tmp = p0; p0 = p1; p1 = p2; p2 = tmp;
    }
    asm volatile("s_waitcnt vmcnt(2)" ::: "memory");    // t = 30
    __builtin_amdgcn_s_barrier();
    __builtin_amdgcn_sched_barrier(0);
    COMPUTE(p0, 30);
    asm volatile("s_waitcnt vmcnt(0)" ::: "memory");    // t = 31
    __builtin_amdgcn_s_barrier();
    __builtin_amdgcn_sched_barrier(0);
    COMPUTE(p1, 31);

#pragma unroll
    for (int mi = 0; mi < 4; ++mi) {
      const int row = r0 + wr * 64 + mi * 16 + kg * 4;
#pragma unroll
      for (int ni = 0; ni < 2; ++ni) {
        const int col = c0 + wc * 32 + ni * 16 + ml;
#pragma unroll
        for (int rj = 0; rj < 4; ++rj)
          yd[(size_t)(row + rj) * H_DIM + col] = f2bf_rne(acc[mi][ni][rj]);
      }
    }
  }
}

// ---------------- combine: out[t] = sum_k w[t,k] * yd[inv[t,k]] ----------------
__global__ void k_combine(const unsigned short* __restrict__ yd, const int* __restrict__ inv,
                          const float* __restrict__ wts, float* __restrict__ out) {
  const int t = blockIdx.x * 4 + (threadIdx.x >> 6);  // one wave per token
  const int lane = threadIdx.x & 63;
  const int i0 = 2 * t, i1 = 2 * t + 1;
  const int r0 = inv[i0], r1 = inv[i1];
  float o[8] = {0.f, 0.f, 0.f, 0.f, 0.f, 0.f, 0.f, 0.f};
  if (r0 >= 0) {
    float w = wts[i0];
    short8 y = *(const short8*)(yd + (size_t)r0 * H_DIM + lane * 8);
#pragma unroll
    for (int j = 0; j < 8; ++j) o[j] += w * bf2f((unsigned short)y[j]);
  }
  if (r1 >= 0) {
    float w = wts[i1];
    short8 y = *(const short8*)(yd + (size_t)r1 * H_DIM + lane * 8);
#pragma unroll
    for (int j = 0; j < 8; ++j) o[j] += w * bf2f((unsigned short)y[j]);
  }
  float4v v0 = {o[0], o[1], o[2], o[3]};
  float4v v1 = {o[4], o[5], o[6], o[7]};
  float4v* dst = (float4v*)(out + (size_t)t * H_DIM + lane * 8);
  dst[0] = v0;
  dst[1] = v1;
}

extern "C" void kernel_launch(void* const* d_in, const int* in_sizes, int n_in,
                              void* d_out, int out_size, void* d_ws, size_t ws_size,
                              hipStream_t stream) {
  const float* hs  = (const float*)d_in[0];  // [T,H]
  const int*   idx = (const int*)d_in[1];    // [T,K]
  const float* wts = (const float*)d_in[2];  // [T,K]
  const float* gup = (const float*)d_in[3];  // [E,2I,H]
  const float* dwn = (const float*)d_in[4];  // [E,H,I]
  float* out = (float*)d_out;                // [T,H]

  char* ws = (char*)d_ws;
  int* counts       = (int*)ws;                             // 128 B used
  int* inv          = (int*)(ws + 1024);                    // 32 KB
  int* slot_token   = (int*)(ws + 1024 + 32768);            // 64 KB
  unsigned short* xd  = (unsigned short*)(ws + 131072);     // 16.8 MB
  unsigned short* act = xd + (size_t)NROWS * H_DIM;         // 33.6 MB
  unsigned short* yd  = xd;  // xd is dead after gemm1; alias

  hipMemsetAsync(counts, 0, E_NUM * sizeof(int), stream);
  k_route<<<NPAIR / 256, 256, 0, stream>>>(idx, counts, slot_token, inv);
  k_gather<<<NROWS / 4, 256, 0, stream>>>(hs, counts, slot_token, xd);
  k_gemm1<<<512, 256, 0, stream>>>(xd, gup, counts, act);   // 32 experts x 16 col tiles
  k_gemm2<<<256, 256, 0, stream>>>(act, dwn, counts, yd);   // 32 experts x 8 col tiles
  k_combine<<<T_TOK / 4, 256, 0, stream>>>(yd, inv, wts, out);
}